// Round 1
// baseline (823.906 us; speedup 1.0000x reference)
//
#include <hip/hip_runtime.h>
#include <cmath>

#define NPTS 1048576
#define TABLE_SZ 524288

struct ResArr { int r[16]; };

__global__ __launch_bounds__(256) void ngp_fused(
    const float* __restrict__ xin, const float* __restrict__ din,
    const float* __restrict__ emb,
    const float* __restrict__ ws0, const float* __restrict__ ws1,
    const float* __restrict__ wc0, const float* __restrict__ wc1,
    const float* __restrict__ wc2,
    float* __restrict__ out, ResArr res)
{
    const int i = blockIdx.x * blockDim.x + threadIdx.x;

    const float px = (xin[3*i+0] + 1.0f) * 0.5f;
    const float py = (xin[3*i+1] + 1.0f) * 0.5f;
    const float pz = (xin[3*i+2] + 1.0f) * 0.5f;

    // ---- hashgrid encode (all levels dense-indexed: (R+1)^3 <= TABLE) ----
    float feat[32];
    #pragma unroll
    for (int l = 0; l < 16; ++l) {
        const int R = res.r[l];
        const float Rf = (float)R;
        const float gx = px * Rf, gy = py * Rf, gz = pz * Rf;
        int x0 = (int)floorf(gx); x0 = x0 < 0 ? 0 : (x0 > R-1 ? R-1 : x0);
        int y0 = (int)floorf(gy); y0 = y0 < 0 ? 0 : (y0 > R-1 ? R-1 : y0);
        int z0 = (int)floorf(gz); z0 = z0 < 0 ? 0 : (z0 > R-1 ? R-1 : z0);
        const float fx = gx - (float)x0, fy = gy - (float)y0, fz = gz - (float)z0;
        const int s1 = R + 1, s2 = s1 * s1;
        const float* tab = emb + (size_t)l * (size_t)(TABLE_SZ * 2);
        const int b = x0 + y0 * s1 + z0 * s2;
        const float2 c000 = *(const float2*)(tab + 2*(b));
        const float2 c100 = *(const float2*)(tab + 2*(b + 1));
        const float2 c010 = *(const float2*)(tab + 2*(b + s1));
        const float2 c110 = *(const float2*)(tab + 2*(b + s1 + 1));
        const float2 c001 = *(const float2*)(tab + 2*(b + s2));
        const float2 c101 = *(const float2*)(tab + 2*(b + s2 + 1));
        const float2 c011 = *(const float2*)(tab + 2*(b + s1 + s2));
        const float2 c111 = *(const float2*)(tab + 2*(b + s1 + s2 + 1));
        const float ux = 1.0f - fx, uy = 1.0f - fy, uz = 1.0f - fz;
        const float w000 = ux*uy*uz, w100 = fx*uy*uz, w010 = ux*fy*uz, w110 = fx*fy*uz;
        const float w001 = ux*uy*fz, w101 = fx*uy*fz, w011 = ux*fy*fz, w111 = fx*fy*fz;
        feat[2*l+0] = w000*c000.x + w100*c100.x + w010*c010.x + w110*c110.x
                    + w001*c001.x + w101*c101.x + w011*c011.x + w111*c111.x;
        feat[2*l+1] = w000*c000.y + w100*c100.y + w010*c010.y + w110*c110.y
                    + w001*c001.y + w101*c101.y + w011*c011.y + w111*c111.y;
    }

    // ---- sigma MLP layer 1: feat[32] @ ws0[32][64], relu ----
    float h[64];
    #pragma unroll
    for (int j = 0; j < 64; ++j) h[j] = 0.0f;
    #pragma unroll
    for (int k = 0; k < 32; ++k) {
        const float a = feat[k];
        #pragma unroll
        for (int j = 0; j < 64; ++j) h[j] = fmaf(a, ws0[k*64+j], h[j]);
    }
    #pragma unroll
    for (int j = 0; j < 64; ++j) h[j] = fmaxf(h[j], 0.0f);

    // ---- sigma MLP layer 2: h[64] @ ws1[64][16] (linear) ----
    float g[16];
    #pragma unroll
    for (int m = 0; m < 16; ++m) g[m] = 0.0f;
    #pragma unroll
    for (int k = 0; k < 64; ++k) {
        const float a = h[k];
        #pragma unroll
        for (int m = 0; m < 16; ++m) g[m] = fmaf(a, ws1[k*16+m], g[m]);
    }

    out[i] = fabsf(g[0]);   // sigma

    // ---- SH encode (degree 4, 16 coeffs) + geo_feat -> hd[31] ----
    const float dx = din[3*i+0], dy = din[3*i+1], dz = din[3*i+2];
    float hd[31];
    {
        const float xx = dx*dx, yy = dy*dy, zz = dz*dz;
        const float xy = dx*dy, yz = dy*dz, xz = dx*dz;
        hd[0]  = 0.28209479177387814f;
        hd[1]  = -0.48860251190291987f * dy;
        hd[2]  =  0.48860251190291987f * dz;
        hd[3]  = -0.48860251190291987f * dx;
        hd[4]  =  1.0925484305920792f * xy;
        hd[5]  = -1.0925484305920792f * yz;
        hd[6]  =  0.94617469575756f * zz - 0.31539156525252005f;
        hd[7]  = -1.0925484305920792f * xz;
        hd[8]  =  0.5462742152960396f * (xx - yy);
        hd[9]  =  0.5900435899266435f * dy * (yy - 3.0f*xx);
        hd[10] =  2.890611442640554f * xy * dz;
        hd[11] =  0.4570457994644657f * dy * (1.0f - 5.0f*zz);
        hd[12] =  0.3731763325901154f * dz * (5.0f*zz - 3.0f);
        hd[13] =  0.4570457994644657f * dx * (1.0f - 5.0f*zz);
        hd[14] =  1.445305721320277f * dz * (xx - yy);
        hd[15] =  0.5900435899266435f * dx * (3.0f*yy - xx);
    }
    #pragma unroll
    for (int m = 1; m < 16; ++m) hd[15+m] = g[m];

    // ---- color layer 0: hd[31] @ wc0[31][64], relu ----
    float c1[64];
    #pragma unroll
    for (int j = 0; j < 64; ++j) c1[j] = 0.0f;
    #pragma unroll
    for (int k = 0; k < 31; ++k) {
        const float a = hd[k];
        #pragma unroll
        for (int j = 0; j < 64; ++j) c1[j] = fmaf(a, wc0[k*64+j], c1[j]);
    }
    #pragma unroll
    for (int j = 0; j < 64; ++j) c1[j] = fmaxf(c1[j], 0.0f);

    // ---- color layer 1: c1[64] @ wc1[64][64], relu ----
    float c2[64];
    #pragma unroll
    for (int j = 0; j < 64; ++j) c2[j] = 0.0f;
    #pragma unroll
    for (int k = 0; k < 64; ++k) {
        const float a = c1[k];
        #pragma unroll
        for (int j = 0; j < 64; ++j) c2[j] = fmaf(a, wc1[k*64+j], c2[j]);
    }
    #pragma unroll
    for (int j = 0; j < 64; ++j) c2[j] = fmaxf(c2[j], 0.0f);

    // ---- color layer 2: c2[64] @ wc2[64][1] ----
    float col = 0.0f;
    #pragma unroll
    for (int k = 0; k < 64; ++k) col = fmaf(c2[k], wc2[k], col);

    out[NPTS + i] = fabsf(col); // color
}

extern "C" void kernel_launch(void* const* d_in, const int* in_sizes, int n_in,
                              void* d_out, int out_size, void* d_ws, size_t ws_size,
                              hipStream_t stream)
{
    const float* x   = (const float*)d_in[0];
    const float* d   = (const float*)d_in[1];
    const float* emb = (const float*)d_in[2];
    const float* ws0 = (const float*)d_in[3];
    const float* ws1 = (const float*)d_in[4];
    const float* wc0 = (const float*)d_in[5];
    const float* wc1 = (const float*)d_in[6];
    const float* wc2 = (const float*)d_in[7];
    float* out = (float*)d_out;

    // Replicate numpy's host-side RESOLUTIONS computation bit-for-bit:
    // _s = exp(log(64/16)/15); R_l = floor(16 * _s**l). The l=15 value sits
    // within ~1e-13 of exactly 64.0, so we must use the same libm double
    // path numpy's scalar math uses rather than hardcoding.
    ResArr res;
    const double s = std::exp(std::log(4.0) / 15.0);
    for (int l = 0; l < 16; ++l)
        res.r[l] = (int)std::floor(16.0 * std::pow(s, (double)l));

    ngp_fused<<<NPTS / 256, 256, 0, stream>>>(x, d, emb, ws0, ws1, wc0, wc1, wc2, out, res);
}

// Round 2
// 424.480 us; speedup vs baseline: 1.9410x; 1.9410x over previous
//
#include <hip/hip_runtime.h>
#include <cmath>

#define NPTS 1048576
#define TABLE_SZ 524288

typedef _Float16 half8 __attribute__((ext_vector_type(8)));
typedef _Float16 half4 __attribute__((ext_vector_type(4)));
typedef float floatx4 __attribute__((ext_vector_type(4)));

#define MFMA16x16x32 __builtin_amdgcn_mfma_f32_16x16x32_f16

// ---------------------------------------------------------------------------
// Pre-pack all MLP weights into f16 MFMA A-fragments (W^T as A operand).
// Fragment layout for mfma_f32_16x16x32_f16 A[m][k] (M=16,K=32):
//   lane l holds row m = l&15, k = 32*kt + (l>>4)*8 + e, e in [0,8).
// Frag table (20 frags, 1 KB each, fragment-major in d_ws):
//   [0,4)  ws0  (in=32,out=64): mt=f,        kt=0
//   [4,6)  ws1  (in=64,out=16): mt=0,        kt=f-4
//   [6,10) wc0  (in=31,out=64): mt=f-6,      kt=0   (k=31 zero-padded)
//   [10,18) wc1 (in=64,out=64): mt=(f-10)>>1, kt=(f-10)&1
//   [18,20) wc2 (in=64,out=1):  mt=0 (m>=1 zero), kt=f-18
// ---------------------------------------------------------------------------
__global__ void prepack_weights(const float* __restrict__ ws0,
                                const float* __restrict__ ws1,
                                const float* __restrict__ wc0,
                                const float* __restrict__ wc1,
                                const float* __restrict__ wc2,
                                half8* __restrict__ wfrag)
{
    const int f = blockIdx.x, l = threadIdx.x;
    const float* W; int Kreal, Mreal, mt, kt;
    if (f < 4)       { W = ws0; Kreal = 32; Mreal = 64; mt = f;          kt = 0;        }
    else if (f < 6)  { W = ws1; Kreal = 64; Mreal = 16; mt = 0;          kt = f - 4;    }
    else if (f < 10) { W = wc0; Kreal = 31; Mreal = 64; mt = f - 6;      kt = 0;        }
    else if (f < 18) { W = wc1; Kreal = 64; Mreal = 64; mt = (f-10)>>1;  kt = (f-10)&1; }
    else             { W = wc2; Kreal = 64; Mreal = 1;  mt = 0;          kt = f - 18;   }

    const int m  = 16*mt + (l & 15);
    const int k0 = 32*kt + (l >> 4)*8;
    half8 hv;
    #pragma unroll
    for (int e = 0; e < 8; ++e) {
        const int k = k0 + e;
        const float v = (m < Mreal && k < Kreal) ? W[k*Mreal + m] : 0.0f;
        hv[e] = (_Float16)v;
    }
    wfrag[f*64 + l] = hv;
}

// ---------------------------------------------------------------------------
// Fused NGP kernel. 4 waves/block, 32 points/wave (wave-private LDS, no
// __syncthreads). Layers computed as Y^T = W^T @ X^T: points ride the
// B/N operand (col = lane&15), features the M operand.
// ---------------------------------------------------------------------------
__global__ __launch_bounds__(256) void ngp_mfma(
    const float* __restrict__ xin, const float* __restrict__ din,
    const float* __restrict__ emb, const half8* __restrict__ wfrag,
    float* __restrict__ out,
    int4 ra, int4 rb, int4 rc, int4 rd)
{
    // main buffer: feats X (cols 0-31) / H, c1, c2 (cols 0-63); stride 72 f16
    __shared__ __align__(16) _Float16 smM[4][32][72];
    // geo feats (hd cols 16-31); stride 24 f16
    __shared__ __align__(16) _Float16 smG[4][32][24];

    const int tid  = threadIdx.x;
    const int w    = tid >> 6, lane = tid & 63;
    const int gbase = (blockIdx.x * 4 + w) * 32;

    // ================= Phase A: hashgrid (2 lanes per point, 8 levels each)
    {
        const int p  = lane & 31;          // point row in wave
        const int hi = lane >> 5;          // which 8-level half
        const int gpt = gbase + p;
        const float px = (xin[3*gpt+0] + 1.0f) * 0.5f;
        const float py = (xin[3*gpt+1] + 1.0f) * 0.5f;
        const float pz = (xin[3*gpt+2] + 1.0f) * 0.5f;

        float ft[16];
        #pragma unroll
        for (int j = 0; j < 8; ++j) {
            int R;
            if      (j == 0) R = hi ? rc.x : ra.x;
            else if (j == 1) R = hi ? rc.y : ra.y;
            else if (j == 2) R = hi ? rc.z : ra.z;
            else if (j == 3) R = hi ? rc.w : ra.w;
            else if (j == 4) R = hi ? rd.x : rb.x;
            else if (j == 5) R = hi ? rd.y : rb.y;
            else if (j == 6) R = hi ? rd.z : rb.z;
            else             R = hi ? rd.w : rb.w;
            const int lv = hi*8 + j;
            const float Rf = (float)R;
            const float gx = px*Rf, gy = py*Rf, gz = pz*Rf;
            int x0 = (int)floorf(gx); x0 = x0 < 0 ? 0 : (x0 > R-1 ? R-1 : x0);
            int y0 = (int)floorf(gy); y0 = y0 < 0 ? 0 : (y0 > R-1 ? R-1 : y0);
            int z0 = (int)floorf(gz); z0 = z0 < 0 ? 0 : (z0 > R-1 ? R-1 : z0);
            const float fx = gx - (float)x0, fy = gy - (float)y0, fz = gz - (float)z0;
            const int s1 = R + 1, s2 = s1 * s1;
            const float* tab = emb + (size_t)lv * (size_t)(TABLE_SZ * 2);
            const int b = x0 + y0*s1 + z0*s2;
            const float2 c000 = *(const float2*)(tab + 2*(b));
            const float2 c100 = *(const float2*)(tab + 2*(b + 1));
            const float2 c010 = *(const float2*)(tab + 2*(b + s1));
            const float2 c110 = *(const float2*)(tab + 2*(b + s1 + 1));
            const float2 c001 = *(const float2*)(tab + 2*(b + s2));
            const float2 c101 = *(const float2*)(tab + 2*(b + s2 + 1));
            const float2 c011 = *(const float2*)(tab + 2*(b + s1 + s2));
            const float2 c111 = *(const float2*)(tab + 2*(b + s1 + s2 + 1));
            // trilinear via chained lerps
            const float a00x = fmaf(fx, c100.x - c000.x, c000.x);
            const float a10x = fmaf(fx, c110.x - c010.x, c010.x);
            const float a01x = fmaf(fx, c101.x - c001.x, c001.x);
            const float a11x = fmaf(fx, c111.x - c011.x, c011.x);
            const float b0x  = fmaf(fy, a10x - a00x, a00x);
            const float b1x  = fmaf(fy, a11x - a01x, a01x);
            ft[2*j+0] = fmaf(fz, b1x - b0x, b0x);
            const float a00y = fmaf(fx, c100.y - c000.y, c000.y);
            const float a10y = fmaf(fx, c110.y - c010.y, c010.y);
            const float a01y = fmaf(fx, c101.y - c001.y, c001.y);
            const float a11y = fmaf(fx, c111.y - c011.y, c011.y);
            const float b0y  = fmaf(fy, a10y - a00y, a00y);
            const float b1y  = fmaf(fy, a11y - a01y, a01y);
            ft[2*j+1] = fmaf(fz, b1y - b0y, b0y);
        }
        half8 v0, v1;
        #pragma unroll
        for (int c = 0; c < 8; ++c) { v0[c] = (_Float16)ft[c]; v1[c] = (_Float16)ft[8+c]; }
        *(half8*)&smM[w][p][16*hi + 0] = v0;
        *(half8*)&smM[w][p][16*hi + 8] = v1;
    }
    asm volatile("" ::: "memory");

    const int n = lane & 15, g = lane >> 4;
    const floatx4 zz = {0.f, 0.f, 0.f, 0.f};

    auto storeQ = [&](int pt, int mt, floatx4 a) {  // relu + f16, cols [16mt+4g, +4)
        half4 hv;
        hv[0] = (_Float16)fmaxf(a[0], 0.f); hv[1] = (_Float16)fmaxf(a[1], 0.f);
        hv[2] = (_Float16)fmaxf(a[2], 0.f); hv[3] = (_Float16)fmaxf(a[3], 0.f);
        *(half4*)&smM[w][pt][16*mt + 4*g] = hv;
    };

    // ================= S0: feats[32] @ ws0 -> H[64], relu
    {
        const half8 A0 = wfrag[0*64+lane], A1 = wfrag[1*64+lane];
        const half8 A2 = wfrag[2*64+lane], A3 = wfrag[3*64+lane];
        #pragma unroll
        for (int nt = 0; nt < 2; ++nt) {
            const int pt = nt*16 + n;
            const half8 B = *(const half8*)&smM[w][pt][8*g];
            floatx4 a0 = MFMA16x16x32(A0, B, zz, 0,0,0);
            floatx4 a1 = MFMA16x16x32(A1, B, zz, 0,0,0);
            floatx4 a2 = MFMA16x16x32(A2, B, zz, 0,0,0);
            floatx4 a3 = MFMA16x16x32(A3, B, zz, 0,0,0);
            storeQ(pt, 0, a0); storeQ(pt, 1, a1); storeQ(pt, 2, a2); storeQ(pt, 3, a3);
        }
    }
    asm volatile("" ::: "memory");

    // ================= S1: H[64] @ ws1 -> G[16] (linear); sigma + geo out
    {
        const half8 A0 = wfrag[4*64+lane], A1 = wfrag[5*64+lane];
        #pragma unroll
        for (int nt = 0; nt < 2; ++nt) {
            const int pt = nt*16 + n;
            const half8 B0 = *(const half8*)&smM[w][pt][ 0 + 8*g];
            const half8 B1 = *(const half8*)&smM[w][pt][32 + 8*g];
            floatx4 acc = MFMA16x16x32(A0, B0, zz, 0,0,0);
            acc = MFMA16x16x32(A1, B1, acc, 0,0,0);
            // lane holds G feats m = 4g + r for point pt
            if (g == 0) {
                out[gbase + pt] = fabsf(acc[0]);             // sigma = |g0|
                smG[w][pt][0]  = (_Float16)acc[1];           // geo col m-1
                smG[w][pt][1]  = (_Float16)acc[2];
                smG[w][pt][2]  = (_Float16)acc[3];
                smG[w][pt][15] = (_Float16)0.f;              // hd[31] pad
            } else {
                smG[w][pt][4*g-1] = (_Float16)acc[0];
                smG[w][pt][4*g+0] = (_Float16)acc[1];
                smG[w][pt][4*g+1] = (_Float16)acc[2];
                smG[w][pt][4*g+2] = (_Float16)acc[3];
            }
        }
    }
    asm volatile("" ::: "memory");

    // ================= C0: hd[32] @ wc0 -> c1[64], relu
    // hd k: 0-15 SH (computed in-register by g=0,1), 16-31 geo (LDS)
    {
        const half8 A0 = wfrag[6*64+lane], A1 = wfrag[7*64+lane];
        const half8 A2 = wfrag[8*64+lane], A3 = wfrag[9*64+lane];
        #pragma unroll
        for (int nt = 0; nt < 2; ++nt) {
            const int pt = nt*16 + n;
            half8 B;
            if (g < 2) {
                const int gpt = gbase + pt;
                const float x = din[3*gpt+0], y = din[3*gpt+1], z = din[3*gpt+2];
                const float xx = x*x, yy = y*y, zzq = z*z;
                const float xy = x*y, yz = y*z, xz = x*z;
                float s[8];
                if (g == 0) {
                    s[0] = 0.28209479177387814f;
                    s[1] = -0.48860251190291987f * y;
                    s[2] =  0.48860251190291987f * z;
                    s[3] = -0.48860251190291987f * x;
                    s[4] =  1.0925484305920792f * xy;
                    s[5] = -1.0925484305920792f * yz;
                    s[6] =  0.94617469575756f * zzq - 0.31539156525252005f;
                    s[7] = -1.0925484305920792f * xz;
                } else {
                    s[0] =  0.5462742152960396f * (xx - yy);
                    s[1] =  0.5900435899266435f * y * (yy - 3.0f*xx);
                    s[2] =  2.890611442640554f * xy * z;
                    s[3] =  0.4570457994644657f * y * (1.0f - 5.0f*zzq);
                    s[4] =  0.3731763325901154f * z * (5.0f*zzq - 3.0f);
                    s[5] =  0.4570457994644657f * x * (1.0f - 5.0f*zzq);
                    s[6] =  1.445305721320277f * z * (xx - yy);
                    s[7] =  0.5900435899266435f * x * (3.0f*yy - xx);
                }
                #pragma unroll
                for (int e = 0; e < 8; ++e) B[e] = (_Float16)s[e];
            } else {
                B = *(const half8*)&smG[w][pt][8*(g-2)];
            }
            floatx4 a0 = MFMA16x16x32(A0, B, zz, 0,0,0);
            floatx4 a1 = MFMA16x16x32(A1, B, zz, 0,0,0);
            floatx4 a2 = MFMA16x16x32(A2, B, zz, 0,0,0);
            floatx4 a3 = MFMA16x16x32(A3, B, zz, 0,0,0);
            storeQ(pt, 0, a0); storeQ(pt, 1, a1); storeQ(pt, 2, a2); storeQ(pt, 3, a3);
        }
    }
    asm volatile("" ::: "memory");

    // ================= C1: c1[64] @ wc1 -> c2[64], relu
    {
        const half8 A0 = wfrag[10*64+lane], A1 = wfrag[11*64+lane];
        const half8 A2 = wfrag[12*64+lane], A3 = wfrag[13*64+lane];
        const half8 A4 = wfrag[14*64+lane], A5 = wfrag[15*64+lane];
        const half8 A6 = wfrag[16*64+lane], A7 = wfrag[17*64+lane];
        #pragma unroll
        for (int nt = 0; nt < 2; ++nt) {
            const int pt = nt*16 + n;
            const half8 B0 = *(const half8*)&smM[w][pt][ 0 + 8*g];
            const half8 B1 = *(const half8*)&smM[w][pt][32 + 8*g];
            floatx4 a0 = MFMA16x16x32(A0, B0, zz, 0,0,0); a0 = MFMA16x16x32(A1, B1, a0, 0,0,0);
            floatx4 a1 = MFMA16x16x32(A2, B0, zz, 0,0,0); a1 = MFMA16x16x32(A3, B1, a1, 0,0,0);
            floatx4 a2 = MFMA16x16x32(A4, B0, zz, 0,0,0); a2 = MFMA16x16x32(A5, B1, a2, 0,0,0);
            floatx4 a3 = MFMA16x16x32(A6, B0, zz, 0,0,0); a3 = MFMA16x16x32(A7, B1, a3, 0,0,0);
            storeQ(pt, 0, a0); storeQ(pt, 1, a1); storeQ(pt, 2, a2); storeQ(pt, 3, a3);
        }
    }
    asm volatile("" ::: "memory");

    // ================= C2: c2[64] @ wc2 -> color (|.|)
    {
        const half8 A0 = wfrag[18*64+lane], A1 = wfrag[19*64+lane];
        #pragma unroll
        for (int nt = 0; nt < 2; ++nt) {
            const int pt = nt*16 + n;
            const half8 B0 = *(const half8*)&smM[w][pt][ 0 + 8*g];
            const half8 B1 = *(const half8*)&smM[w][pt][32 + 8*g];
            floatx4 acc = MFMA16x16x32(A0, B0, zz, 0,0,0);
            acc = MFMA16x16x32(A1, B1, acc, 0,0,0);
            if (g == 0) out[NPTS + gbase + pt] = fabsf(acc[0]);
        }
    }
}

extern "C" void kernel_launch(void* const* d_in, const int* in_sizes, int n_in,
                              void* d_out, int out_size, void* d_ws, size_t ws_size,
                              hipStream_t stream)
{
    const float* x   = (const float*)d_in[0];
    const float* d   = (const float*)d_in[1];
    const float* emb = (const float*)d_in[2];
    const float* ws0 = (const float*)d_in[3];
    const float* ws1 = (const float*)d_in[4];
    const float* wc0 = (const float*)d_in[5];
    const float* wc1 = (const float*)d_in[6];
    const float* wc2 = (const float*)d_in[7];
    float* out = (float*)d_out;
    half8* wfrag = (half8*)d_ws;   // 20 KB of weight fragments

    // Replicate numpy's host-side RESOLUTIONS computation bit-for-bit.
    int r[16];
    const double s = std::exp(std::log(4.0) / 15.0);
    for (int l = 0; l < 16; ++l)
        r[l] = (int)std::floor(16.0 * std::pow(s, (double)l));
    const int4 ra = {r[0],  r[1],  r[2],  r[3]};
    const int4 rb = {r[4],  r[5],  r[6],  r[7]};
    const int4 rc = {r[8],  r[9],  r[10], r[11]};
    const int4 rd = {r[12], r[13], r[14], r[15]};

    prepack_weights<<<20, 64, 0, stream>>>(ws0, ws1, wc0, wc1, wc2, wfrag);
    ngp_mfma<<<NPTS / 128, 256, 0, stream>>>(x, d, emb, wfrag, out, ra, rb, rc, rd);
}